// Round 7
// baseline (209.647 us; speedup 1.0000x reference)
//
#include <hip/hip_runtime.h>

#define D   256
#define BM  64      // rows per block
#define BN  128     // codes per n-group

typedef __attribute__((ext_vector_type(8))) short v8s;   // 8 bf16 = 4 VGPR
typedef __attribute__((ext_vector_type(4))) float v4f;
#define MFMA16 __builtin_amdgcn_mfma_f32_16x16x32_bf16

static __device__ inline unsigned short f2bf(float f) {          // RNE
    unsigned u = __float_as_uint(f);
    return (unsigned short)((u + 0x7fffu + ((u >> 16) & 1u)) >> 16);
}
static __device__ inline float bf2f(unsigned short s) {
    return __uint_as_float(((unsigned)s) << 16);
}

// async global->LDS, 16 B per lane; LDS dest wave-uniform (HW adds lane*16).
static __device__ inline void gl_lds16(const unsigned short* g, unsigned short* l) {
    __builtin_amdgcn_global_load_lds(
        (const __attribute__((address_space(1))) unsigned int*)g,
        (__attribute__((address_space(3))) unsigned int*)l, 16, 0, 0);
}

// ---------------- kernel 1: c2 + codebook -> bf16 hi/lo stage-major swizzled ----------------
// Stage s = g*8 + kstep covers codes [g*128, g*128+128) x k [kstep*32, +32).
// Granule (16 B = 8 bf16) at index s*512 + seg*128 + (n ^ seg), seg = k-octet 0..3.
// Lane-linear DMA of 512 granules reproduces this in LDS; MFMA read octets
// (col 0..7, seg const) hit granule-groups (col^seg)&7 -> conflict-free.
__global__ void vq_prep(const float* __restrict__ cb, float* __restrict__ c2,
                        unsigned short* __restrict__ cbh, unsigned short* __restrict__ cbl) {
    const int t    = threadIdx.x;                 // 256
    const int code = blockIdx.x * 32 + (t >> 3);  // 64 blocks x 32 codes
    const int g    = code >> 7;
    const int nloc = code & 127;
    const int o    = t & 7;                       // k-octet slice
    float s = 0.0f;
    #pragma unroll
    for (int i = 0; i < 4; ++i) {
        const int ko = i * 8 + o;                 // k-octet 0..31
        const float* src = cb + (size_t)code * D + ko * 8;
        const float4 f0 = *reinterpret_cast<const float4*>(src);
        const float4 f1 = *reinterpret_cast<const float4*>(src + 4);
        const float f[8] = {f0.x, f0.y, f0.z, f0.w, f1.x, f1.y, f1.z, f1.w};
        v8s h, l;
        #pragma unroll
        for (int j = 0; j < 8; ++j) {
            s += f[j] * f[j];
            unsigned short hb = f2bf(f[j]);
            h[j] = (short)hb;
            l[j] = (short)f2bf(f[j] - bf2f(hb));
        }
        const int stage = g * 8 + (ko >> 2);
        const int seg   = ko & 3;
        const size_t G  = (size_t)stage * 512 + seg * 128 + (nloc ^ seg);
        *reinterpret_cast<v8s*>(cbh + G * 8) = h;
        *reinterpret_cast<v8s*>(cbl + G * 8) = l;
    }
    s += __shfl_down(s, 4, 64);
    s += __shfl_down(s, 2, 64);
    s += __shfl_down(s, 1, 64);
    if (o == 0) c2[code] = s;
}

// ---------------- kernel 2: MFMA argmin + fused gather/loss + last-block reduce ----------------
#define SLOT_H(i) ((i) == 0 ? sh0 : (i) == 1 ? sh1 : (i) == 2 ? sh2 : sh3)
#define SLOT_L(i) ((i) == 0 ? sl0 : (i) == 1 ? sl1 : (i) == 2 ? sl2 : sl3)

__global__ __launch_bounds__(256, 2) void vq_argmin_mfma(
        const float* __restrict__ x, const float* __restrict__ cb,
        const unsigned short* __restrict__ cbh, const unsigned short* __restrict__ cbl,
        const float* __restrict__ c2, float* __restrict__ idx_out,
        float* __restrict__ qout, float* __restrict__ partial,
        int* __restrict__ counter, float* __restrict__ loss, float scale, int N) {
    __shared__ unsigned short sh0[4096], sh1[4096], sh2[4096], sh3[4096];  // hi ring, 4x8 KB
    __shared__ unsigned short sl0[4096], sl1[4096], sl2[4096], sl3[4096];  // lo ring, 4x8 KB
    __shared__ float c2s[2048];          // 8 KB
    __shared__ float mrg_v[BM * 2];
    __shared__ int   mrg_i[BM * 2];
    __shared__ int   idx_sh[BM];
    __shared__ float wsum[4];
    __shared__ int   amLast;

    const int tid  = threadIdx.x;
    const int w    = tid >> 6;
    const int lane = tid & 63;
    const int col  = lane & 15;
    const int quad = lane >> 4;          // = seg for KC=32
    const int mg   = w >> 1;
    const int ng   = w & 1;
    const int m0   = blockIdx.x * BM;
    const int n_groups = N >> 7;
    const int smask    = n_groups * 8 - 1;   // 127

    // per-wave DMA source base: this wave stages granules [w*128, w*128+128) per stage
    const unsigned short* gh0 = cbh + ((size_t)(w * 128 + lane)) * 8;
    const unsigned short* gl0 = cbl + ((size_t)(w * 128 + lane)) * 8;

    // prologue: issue stage 0 and 1 DMA (slots 0,1) before anything else
    gl_lds16(gh0,            sh0 + (w * 128) * 8);
    gl_lds16(gh0 + 64 * 8,   sh0 + (w * 128 + 64) * 8);
    gl_lds16(gl0,            sl0 + (w * 128) * 8);
    gl_lds16(gl0 + 64 * 8,   sl0 + (w * 128 + 64) * 8);
    gl_lds16(gh0 + 4096,     sh1 + (w * 128) * 8);
    gl_lds16(gh0 + 4096 + 512, sh1 + (w * 128 + 64) * 8);
    gl_lds16(gl0 + 4096,     sl1 + (w * 128) * 8);
    gl_lds16(gl0 + 4096 + 512, sl1 + (w * 128 + 64) * 8);

    // c2 -> LDS (keeps the inner loop free of extra vmem ops)
    {
        const float4 a = *reinterpret_cast<const float4*>(c2 + tid * 8);
        const float4 b = *reinterpret_cast<const float4*>(c2 + tid * 8 + 4);
        *reinterpret_cast<float4*>(&c2s[tid * 8])     = a;
        *reinterpret_cast<float4*>(&c2s[tid * 8 + 4]) = b;
    }

    // A-frags: rows m0 + mg*32 + mt*16 + col, full K, hi+lo (128 VGPR)
    v8s xh[2][8], xl[2][8];
    #pragma unroll
    for (int mt = 0; mt < 2; ++mt) {
        const float* xr = x + (size_t)(m0 + mg * 32 + mt * 16 + col) * D;
        #pragma unroll
        for (int ks = 0; ks < 8; ++ks) {
            const int kb = ks * 32 + quad * 8;
            const float4 f0 = *reinterpret_cast<const float4*>(xr + kb);
            const float4 f1 = *reinterpret_cast<const float4*>(xr + kb + 4);
            float f[8] = {f0.x, f0.y, f0.z, f0.w, f1.x, f1.y, f1.z, f1.w};
            v8s h, l;
            #pragma unroll
            for (int j = 0; j < 8; ++j) {
                unsigned short hb = f2bf(f[j]);
                h[j] = (short)hb;
                l[j] = (short)f2bf(f[j] - bf2f(hb));
            }
            xh[mt][ks] = h; xl[mt][ks] = l;
        }
    }

    float runmin[2][4];
    int   runidx[2][4];
    #pragma unroll
    for (int mt = 0; mt < 2; ++mt)
        #pragma unroll
        for (int r = 0; r < 4; ++r) { runmin[mt][r] = 3.4e38f; runidx[mt][r] = 0; }

    v4f acc[4][2];
    #pragma unroll
    for (int nt = 0; nt < 4; ++nt)
        #pragma unroll
        for (int mt = 0; mt < 2; ++mt) acc[nt][mt] = 0.0f;

    asm volatile("s_waitcnt lgkmcnt(0)" ::: "memory");   // c2s writes done pre-barrier

    for (int g = 0; g < n_groups; ++g) {
        #pragma unroll
        for (int ss = 0; ss < 8; ++ss) {                 // stage = g*8+ss; g*8 % 8 == 0
            // own stage-ss DMAs complete (4 newest = stage ss+1), then block barrier
            asm volatile("s_waitcnt vmcnt(4)\n\ts_barrier" ::: "memory");

            // prefetch stage+2 into slot (ss+2)&3 (wraps to stage 0/1 at the end: dummy)
            {
                const int pstage = (g * 8 + ss + 2) & smask;
                const unsigned short* gh = gh0 + (size_t)pstage * 4096;
                const unsigned short* gl = gl0 + (size_t)pstage * 4096;
                unsigned short* lh = SLOT_H((ss + 2) & 3);
                unsigned short* ll = SLOT_L((ss + 2) & 3);
                gl_lds16(gh,           lh + (w * 128) * 8);
                gl_lds16(gh + 64 * 8,  lh + (w * 128 + 64) * 8);
                gl_lds16(gl,           ll + (w * 128) * 8);
                gl_lds16(gl + 64 * 8,  ll + (w * 128 + 64) * 8);
            }
            __builtin_amdgcn_sched_barrier(0);   // keep DMA issue above the MFMA section

            const unsigned short* LH = SLOT_H(ss & 3);
            const unsigned short* LL = SLOT_L(ss & 3);
            #pragma unroll
            for (int nt = 0; nt < 4; ++nt) {
                const int p = quad * 128 + ((ng * 64 + nt * 16 + col) ^ quad);
                const v8s ch = *reinterpret_cast<const v8s*>(&LH[p * 8]);
                const v8s cl = *reinterpret_cast<const v8s*>(&LL[p * 8]);
                #pragma unroll
                for (int mt = 0; mt < 2; ++mt) {
                    acc[nt][mt] = MFMA16(xh[mt][ss], ch, acc[nt][mt], 0, 0, 0);
                    acc[nt][mt] = MFMA16(xl[mt][ss], ch, acc[nt][mt], 0, 0, 0);
                    acc[nt][mt] = MFMA16(xh[mt][ss], cl, acc[nt][mt], 0, 0, 0);
                }
            }
        }
        // finalize this n-group (c2 from LDS; no vmem)
        #pragma unroll
        for (int nt = 0; nt < 4; ++nt) {
            const int n   = g * BN + ng * 64 + nt * 16 + col;
            const float c2n = c2s[n];
            #pragma unroll
            for (int mt = 0; mt < 2; ++mt) {
                #pragma unroll
                for (int r = 0; r < 4; ++r) {
                    const float s = c2n - 2.0f * acc[nt][mt][r];
                    if (s < runmin[mt][r]) { runmin[mt][r] = s; runidx[mt][r] = n; }
                }
                acc[nt][mt] = 0.0f;
            }
        }
    }

    // ---- in-wave argmin across col (lane bits 0..3), then 2-way LDS merge over ng ----
    #pragma unroll
    for (int mt = 0; mt < 2; ++mt)
        #pragma unroll
        for (int r = 0; r < 4; ++r) {
            float v = runmin[mt][r];
            int  id = runidx[mt][r];
            #pragma unroll
            for (int m = 8; m >= 1; m >>= 1) {
                const float ov = __shfl_xor(v, m, 64);
                const int   oi = __shfl_xor(id, m, 64);
                if (ov < v || (ov == v && oi < id)) { v = ov; id = oi; }
            }
            if (col == 0) {
                const int row = mg * 32 + mt * 16 + quad * 4 + r;
                mrg_v[row * 2 + ng] = v;
                mrg_i[row * 2 + ng] = id;
            }
        }
    __syncthreads();   // full drain fine: dummy DMAs may still fly, let them land
    if (tid < 64) {
        float best = mrg_v[tid * 2];
        int   bidx = mrg_i[tid * 2];
        const float v2 = mrg_v[tid * 2 + 1];
        const int   i2 = mrg_i[tid * 2 + 1];
        if (v2 < best || (v2 == best && i2 < bidx)) { best = v2; bidx = i2; }
        idx_out[m0 + tid] = (float)bidx;
        idx_sh[tid] = bidx;
    }
    __syncthreads();

    // ---- fused gather + loss over this block's 64 rows (x tile is L2-hot) ----
    const float* xg2 = x + (size_t)m0 * D;
    float s = 0.0f;
    #pragma unroll
    for (int i = 0; i < 16; ++i) {
        const int gq  = i * 256 + tid;      // float4-granule, 4096 total
        const int row = gq >> 6;
        const int k4  = (gq & 63) * 4;
        const int idx = idx_sh[row];
        const float4 c  = *reinterpret_cast<const float4*>(cb  + (size_t)idx * D + k4);
        const float4 xv = *reinterpret_cast<const float4*>(xg2 + (size_t)row * D + k4);
        *reinterpret_cast<float4*>(qout + (size_t)(m0 + row) * D + k4) = c;
        const float dx = c.x - xv.x, dy = c.y - xv.y, dz = c.z - xv.z, dw = c.w - xv.w;
        s += dx * dx + dy * dy + dz * dz + dw * dw;
    }
    #pragma unroll
    for (int off = 32; off > 0; off >>= 1) s += __shfl_down(s, off, 64);
    if ((tid & 63) == 0) wsum[tid >> 6] = s;
    __syncthreads();
    if (tid == 0) {
        partial[blockIdx.x] = wsum[0] + wsum[1] + wsum[2] + wsum[3];
        __threadfence();
        amLast = (atomicAdd(counter, 1) == (int)gridDim.x - 1);
    }
    __syncthreads();
    if (amLast) {
        __threadfence();
        float t = 0.0f;
        for (int i = tid; i < (int)gridDim.x; i += 256) t += partial[i];
        #pragma unroll
        for (int off = 32; off > 0; off >>= 1) t += __shfl_down(t, off, 64);
        if ((tid & 63) == 0) wsum[tid >> 6] = t;
        __syncthreads();
        if (tid == 0) loss[0] = (wsum[0] + wsum[1] + wsum[2] + wsum[3]) * scale;
    }
}

extern "C" void kernel_launch(void* const* d_in, const int* in_sizes, int n_in,
                              void* d_out, int out_size, void* d_ws, size_t ws_size,
                              hipStream_t stream) {
    const float* x  = (const float*)d_in[0];
    const float* cb = (const float*)d_in[1];
    const int M = in_sizes[0] / D;   // 32768
    const int N = in_sizes[1] / D;   // 2048

    float* qout    = (float*)d_out;
    float* idx_out = qout + (size_t)M * D;
    float* loss    = idx_out + M;

    // ws: c2 [0,8K) | cbh [8K,+1M) | cbl [+1M) | partial [512 f] | counter [1 int]
    char* wsb = (char*)d_ws;
    float*          c2      = (float*)wsb;
    unsigned short* cbh     = (unsigned short*)(wsb + 8192);
    unsigned short* cbl     = cbh + (size_t)N * D;
    float*          partial = (float*)(wsb + 8192 + 2 * (size_t)N * D * sizeof(unsigned short));
    int*            counter = (int*)(partial + M / BM);

    hipMemsetAsync(counter, 0, sizeof(int), stream);
    vq_prep<<<N / 32, 256, 0, stream>>>(cb, c2, cbh, cbl);
    const float scale = 2.0f / (float)((size_t)M * D);
    vq_argmin_mfma<<<M / BM, 256, 0, stream>>>(x, cb, cbh, cbl, c2, idx_out, qout,
                                               partial, counter, loss, scale, N);
}